// Round 3
// baseline (181.204 us; speedup 1.0000x reference)
//
#include <hip/hip_runtime.h>
#include <hip/hip_bf16.h>

// B=4, T=4096, E=1024, H=64.
// d_ws: kmat bf16 [b][t][d] | qmat bf16 [b][t][d] (prescaled by 0.125) |
//       vT bf16 [b][d][t]   | opart f32 [S][16384][64] | mpart,lpart f32 [S][16384]

typedef __attribute__((ext_vector_type(8))) short short8;
typedef __attribute__((ext_vector_type(4))) short short4v;
typedef __attribute__((ext_vector_type(4))) float f32x4;

__device__ inline short f2bf(float f) {
  union { __hip_bfloat16 h; short s; } u; u.h = __float2bfloat16(f); return u.s;
}
__device__ inline unsigned pack_bf2(float lo, float hi) {
  union { __hip_bfloat16 h; unsigned short s; } a, b;
  a.h = __float2bfloat16(lo); b.h = __float2bfloat16(hi);
  return (unsigned)a.s | ((unsigned)b.s << 16);
}

#define PBM 64

// Fused projections: one x read, three GEMMs. q prescaled by 1/sqrt(H).
// v written transposed: vT[b][d][t].
__global__ __launch_bounds__(256) void proj_fused_kernel(
    const float* __restrict__ x,
    const float* __restrict__ Wk, const float* __restrict__ Wq, const float* __restrict__ Wv,
    short* __restrict__ kout, short* __restrict__ qout, short* __restrict__ vTout)
{
  __shared__ __align__(16) short xl[PBM][72];
  __shared__ __align__(16) short wl[3][64][72];   // wl[m][n][k]

  const int tid  = threadIdx.x;
  const int w    = tid >> 6;
  const int lane = tid & 63;
  const int lr   = lane & 15;
  const int lg   = lane >> 4;
  const int rowbase = blockIdx.x * PBM;
  const float* Wm[3] = {Wk, Wq, Wv};

  f32x4 acc[3][4];
#pragma unroll
  for (int m3 = 0; m3 < 3; ++m3)
#pragma unroll
    for (int ct = 0; ct < 4; ++ct)
      acc[m3][ct] = (f32x4){0.f, 0.f, 0.f, 0.f};

  for (int kb = 0; kb < 1024; kb += 64) {
    __syncthreads();
    // stage x tile 64x64 -> bf16 (1024 float4 / 256 thr = 4 each)
#pragma unroll
    for (int p = 0; p < 4; ++p) {
      int idx4 = p * 256 + tid;
      int r = idx4 >> 4;
      int c = (idx4 & 15) << 2;
      float4 vv = *reinterpret_cast<const float4*>(&x[(size_t)(rowbase + r) * 1024 + kb + c]);
      short4v sv;
      sv.x = f2bf(vv.x); sv.y = f2bf(vv.y); sv.z = f2bf(vv.z); sv.w = f2bf(vv.w);
      *reinterpret_cast<short4v*>(&xl[r][c]) = sv;
    }
    // stage the three W tiles transposed: wl[m][n][kk]
#pragma unroll
    for (int m3 = 0; m3 < 3; ++m3) {
      const float* W = Wm[m3];
#pragma unroll
      for (int p = 0; p < 4; ++p) {
        int idx4 = p * 256 + tid;
        int kr = idx4 >> 4;
        int c  = (idx4 & 15) << 2;
        float4 vv = *reinterpret_cast<const float4*>(&W[(size_t)(kb + kr) * 64 + c]);
        wl[m3][c + 0][kr] = f2bf(vv.x);
        wl[m3][c + 1][kr] = f2bf(vv.y);
        wl[m3][c + 2][kr] = f2bf(vv.z);
        wl[m3][c + 3][kr] = f2bf(vv.w);
      }
    }
    __syncthreads();

#pragma unroll
    for (int ks = 0; ks < 2; ++ks) {
      short8 a = *reinterpret_cast<const short8*>(&xl[16 * w + lr][ks * 32 + lg * 8]);
#pragma unroll
      for (int m3 = 0; m3 < 3; ++m3)
#pragma unroll
        for (int ct = 0; ct < 4; ++ct) {
          short8 b = *reinterpret_cast<const short8*>(&wl[m3][16 * ct + lr][ks * 32 + lg * 8]);
          acc[m3][ct] = __builtin_amdgcn_mfma_f32_16x16x32_bf16(a, b, acc[m3][ct], 0, 0, 0);
        }
    }
  }

  // epilogue. D layout: col = lr, row = lg*4+j.
  const int bb    = rowbase >> 12;          // batch
  const int tloc0 = (rowbase & 4095) + 16 * w;
#pragma unroll
  for (int ct = 0; ct < 4; ++ct) {
#pragma unroll
    for (int j = 0; j < 4; ++j) {
      int row = rowbase + 16 * w + 4 * lg + j;
      kout[(size_t)row * 64 + 16 * ct + lr] = f2bf(acc[0][ct][j]);
      qout[(size_t)row * 64 + 16 * ct + lr] = f2bf(acc[1][ct][j] * 0.125f);
    }
    short4v vv;
    vv.x = f2bf(acc[2][ct][0]); vv.y = f2bf(acc[2][ct][1]);
    vv.z = f2bf(acc[2][ct][2]); vv.w = f2bf(acc[2][ct][3]);
    size_t vidx = (size_t)bb * 64 * 4096 + (size_t)(16 * ct + lr) * 4096 + tloc0 + 4 * lg;
    *reinterpret_cast<short4v*>(&vTout[vidx]) = vv;
  }
}

// Barrier-free KV-split flash attention.
// Swapped QK^T (mfma(K,Q)) => lane owns one q-row (qrow = lr); swapped PV
// (mfma(V^T,P^T)) keeps O^T consistent. P transposed via per-wave packed LDS.
__global__ __launch_bounds__(256, 4) void attn_split_kernel(
    const short* __restrict__ qm, const short* __restrict__ km, const short* __restrict__ vT,
    float* __restrict__ opart, float* __restrict__ mpart, float* __restrict__ lpart,
    int S, int chunkTiles)
{
  const int qidx  = blockIdx.x / S;
  const int split = blockIdx.x % S;
  const int b  = qidx >> 6;
  const int qt = qidx & 63;
  const int tid  = threadIdx.x;
  const int w    = tid >> 6;
  const int lane = tid & 63;
  const int lr   = lane & 15;
  const int lg   = lane >> 4;

  __shared__ unsigned pl[4][16][36];   // per-wave packed P rows (u32 = 2 bf16); no barriers

  const short* qb = qm + ((size_t)(b * 4096 + qt * 64 + 16 * w)) * 64;
  const short* kb = km + (size_t)b * 4096 * 64;
  const short* vb = vT + (size_t)b * 64 * 4096;

  short8 qf[2];
#pragma unroll
  for (int ks = 0; ks < 2; ++ks)
    qf[ks] = *reinterpret_cast<const short8*>(&qb[lr * 64 + ks * 32 + lg * 8]);

  float m = -3e38f, l = 0.f;
  f32x4 o[4];
#pragma unroll
  for (int dt = 0; dt < 4; ++dt) o[dt] = (f32x4){0.f, 0.f, 0.f, 0.f};

  const int kt0 = split * chunkTiles;
  for (int kt = kt0; kt < kt0 + chunkTiles; ++kt) {
    const short* kRow = kb + (size_t)kt * 64 * 64;

    // S^T = K Q^T : lane holds s[kt16][j] = S[qrow=lr][key = 16*kt16 + 4*lg + j]
    f32x4 s[4];
#pragma unroll
    for (int kt16 = 0; kt16 < 4; ++kt16) s[kt16] = (f32x4){0.f, 0.f, 0.f, 0.f};
#pragma unroll
    for (int ks = 0; ks < 2; ++ks)
#pragma unroll
      for (int kt16 = 0; kt16 < 4; ++kt16) {
        short8 kf = *reinterpret_cast<const short8*>(
            &kRow[(kt16 * 16 + lr) * 64 + ks * 32 + lg * 8]);
        s[kt16] = __builtin_amdgcn_mfma_f32_16x16x32_bf16(kf, qf[ks], s[kt16], 0, 0, 0);
      }

    // lane-local softmax over this row's 16 scores (scale pre-folded into q)
    float pmax = s[0][0];
#pragma unroll
    for (int kt16 = 0; kt16 < 4; ++kt16)
#pragma unroll
      for (int jj = 0; jj < 4; ++jj) pmax = fmaxf(pmax, s[kt16][jj]);
    pmax = fmaxf(pmax, __shfl_xor(pmax, 16));
    pmax = fmaxf(pmax, __shfl_xor(pmax, 32));

    if (__any(pmax > m + 8.f)) {          // T13 defer-max
      float mn    = fmaxf(m, pmax);
      float alpha = __expf(m - mn);
      l *= alpha;
#pragma unroll
      for (int dt = 0; dt < 4; ++dt) o[dt] *= alpha;
      m = mn;
    }

    // p = exp(s - m) in place; accumulate per-lane partial l (cross-lane deferred)
#pragma unroll
    for (int kt16 = 0; kt16 < 4; ++kt16)
#pragma unroll
      for (int jj = 0; jj < 4; ++jj) s[kt16][jj] = __expf(s[kt16][jj] - m);
    float ps = 0.f;
#pragma unroll
    for (int kt16 = 0; kt16 < 4; ++kt16)
      ps += (s[kt16][0] + s[kt16][1]) + (s[kt16][2] + s[kt16][3]);
    l += ps;

    // write packed P into the wave-private transpose buffer
#pragma unroll
    for (int kt16 = 0; kt16 < 4; ++kt16) {
      pl[w][lr][8 * kt16 + 2 * lg + 0] = pack_bf2(s[kt16][0], s[kt16][1]);
      pl[w][lr][8 * kt16 + 2 * lg + 1] = pack_bf2(s[kt16][2], s[kt16][3]);
    }
    asm volatile("s_waitcnt lgkmcnt(0)" ::: "memory");

    // O^T += V^T P^T : A = vT rows (global, L2), B = P^T from pl
#pragma unroll
    for (int ks = 0; ks < 2; ++ks) {
      short8 pf = *reinterpret_cast<const short8*>(&pl[w][lr][16 * ks + 4 * lg]);
#pragma unroll
      for (int dt = 0; dt < 4; ++dt) {
        short8 vf = *reinterpret_cast<const short8*>(
            &vb[(size_t)(16 * dt + lr) * 4096 + kt * 64 + ks * 32 + lg * 8]);
        o[dt] = __builtin_amdgcn_mfma_f32_16x16x32_bf16(vf, pf, o[dt], 0, 0, 0);
      }
    }
  }

  // epilogue: lane owns qrow = lr, d = 16*dt + 4*lg + j
  l += __shfl_xor(l, 16);
  l += __shfl_xor(l, 32);
  const int rowg = b * 4096 + qt * 64 + 16 * w + lr;
  float* ob = opart + ((size_t)split * 16384 + rowg) * 64;
#pragma unroll
  for (int dt = 0; dt < 4; ++dt)
    *reinterpret_cast<f32x4*>(&ob[16 * dt + 4 * lg]) = o[dt];
  if (lane < 16) {
    mpart[split * 16384 + rowg] = m;
    lpart[split * 16384 + rowg] = l;
  }
}

__global__ __launch_bounds__(256) void merge_kernel(
    const float* __restrict__ opart, const float* __restrict__ mpart,
    const float* __restrict__ lpart, float* __restrict__ out, int S)
{
  int gid = blockIdx.x * 256 + threadIdx.x;   // over 16384*16 float4s
  int row = gid >> 4;
  int c4  = (gid & 15) << 2;
  float M = -3e38f;
  for (int s = 0; s < S; ++s) M = fmaxf(M, mpart[s * 16384 + row]);
  float denom = 0.f;
  float ax = 0.f, ay = 0.f, az = 0.f, aw = 0.f;
  for (int s = 0; s < S; ++s) {
    float wgt = __expf(mpart[s * 16384 + row] - M);
    denom += wgt * lpart[s * 16384 + row];
    float4 op = *reinterpret_cast<const float4*>(&opart[((size_t)s * 16384 + row) * 64 + c4]);
    ax += wgt * op.x; ay += wgt * op.y; az += wgt * op.z; aw += wgt * op.w;
  }
  float inv = 1.f / denom;
  float4 r; r.x = ax * inv; r.y = ay * inv; r.z = az * inv; r.w = aw * inv;
  *reinterpret_cast<float4*>(&out[(size_t)row * 64 + c4]) = r;
}

extern "C" void kernel_launch(void* const* d_in, const int* in_sizes, int n_in,
                              void* d_out, int out_size, void* d_ws, size_t ws_size,
                              hipStream_t stream) {
  const float* x  = (const float*)d_in[0];
  const float* Wk = (const float*)d_in[1];
  const float* Wq = (const float*)d_in[2];
  const float* Wv = (const float*)d_in[3];

  const size_t MH = (size_t)16384 * 64;
  short* kmat = (short*)d_ws;
  short* qmat = kmat + MH;
  short* vTm  = qmat + MH;

  proj_fused_kernel<<<16384 / PBM, 256, 0, stream>>>(x, Wk, Wq, Wv, kmat, qmat, vTm);

  const size_t qkv_bytes = 3 * MH * sizeof(short);                 // 6 MB
  const size_t o_bytes   = MH * sizeof(float);                     // 4 MB / split
  const size_t ml_bytes  = 2 * (size_t)16384 * sizeof(float);
  int S = 8;
  while (S > 1 && qkv_bytes + (size_t)S * (o_bytes + ml_bytes) > ws_size) S >>= 1;

  float* opart = (float*)((char*)d_ws + qkv_bytes);
  float* mpart = opart + (size_t)S * MH;
  float* lpart = mpart + (size_t)S * 16384;
  attn_split_kernel<<<256 * S, 256, 0, stream>>>(qmat, kmat, vTm,
                                                 opart, mpart, lpart, S, 64 / S);
  merge_kernel<<<1024, 256, 0, stream>>>(opart, mpart, lpart, (float*)d_out, S);
}

// Round 4
// 83.957 us; speedup vs baseline: 2.1583x; 2.1583x over previous
//
#include <hip/hip_runtime.h>
#include <hip/hip_bf16.h>

// B=4, T=4096, E=1024, H=64.
// d_ws: kmat bf16 [b][t][d] | qmat bf16 [b][t][d] (prescaled 0.125*log2e) |
//       vT bf16 [b][d][t]   | opart f32 [S][16384][64] | mpart,lpart f32 [S][16384]
// Attention math done in exp2 domain (q prescaled); merge uses exp2f.

typedef __attribute__((ext_vector_type(8))) short short8;
typedef __attribute__((ext_vector_type(4))) short short4v;
typedef __attribute__((ext_vector_type(4))) float f32x4;

__device__ inline short f2bf(float f) {
  union { __hip_bfloat16 h; short s; } u; u.h = __float2bfloat16(f); return u.s;
}
__device__ inline unsigned pack_bf2(float lo, float hi) {
  union { __hip_bfloat16 h; unsigned short s; } a, b;
  a.h = __float2bfloat16(lo); b.h = __float2bfloat16(hi);
  return (unsigned)a.s | ((unsigned)b.s << 16);
}

#define PROJ_BM 128
#define LOG2E 1.44269504f

// C = x[16384,1024] @ W[1024,64]; y selects Wk/Wq/Wv. q prescaled; v transposed.
__global__ __launch_bounds__(256) void proj_kernel(
    const float* __restrict__ x,
    const float* __restrict__ Wk, const float* __restrict__ Wq, const float* __restrict__ Wv,
    short* __restrict__ kout, short* __restrict__ qout, short* __restrict__ vTout)
{
  const float* W; short* out;
  if (blockIdx.y == 0)      { W = Wk; out = kout; }
  else if (blockIdx.y == 1) { W = Wq; out = qout; }
  else                      { W = Wv; out = vTout; }

  __shared__ __align__(16) short xl[PROJ_BM][72];
  __shared__ __align__(16) short wl[64][72];   // W^T: [col][k]

  const int tid = threadIdx.x;
  const int w   = tid >> 6;
  const int lane = tid & 63;
  const int lr  = lane & 15;
  const int lg  = lane >> 4;
  const int rowbase = blockIdx.x * PROJ_BM;

  f32x4 acc[2][4];
#pragma unroll
  for (int i = 0; i < 2; ++i)
#pragma unroll
    for (int j = 0; j < 4; ++j)
      acc[i][j] = (f32x4){0.f, 0.f, 0.f, 0.f};

  for (int kb = 0; kb < 1024; kb += 64) {
    __syncthreads();
#pragma unroll
    for (int p = 0; p < 8; ++p) {
      int idx4 = p * 256 + tid;
      int r  = idx4 >> 4;
      int c  = (idx4 & 15) << 2;
      float4 vv = *reinterpret_cast<const float4*>(&x[(size_t)(rowbase + r) * 1024 + kb + c]);
      short4v sv;
      sv.x = f2bf(vv.x); sv.y = f2bf(vv.y); sv.z = f2bf(vv.z); sv.w = f2bf(vv.w);
      *reinterpret_cast<short4v*>(&xl[r][c]) = sv;
    }
#pragma unroll
    for (int p = 0; p < 4; ++p) {
      int idx4 = p * 256 + tid;
      int kr = idx4 >> 4;
      int c  = (idx4 & 15) << 2;
      float4 vv = *reinterpret_cast<const float4*>(&W[(size_t)(kb + kr) * 64 + c]);
      wl[c + 0][kr] = f2bf(vv.x);
      wl[c + 1][kr] = f2bf(vv.y);
      wl[c + 2][kr] = f2bf(vv.z);
      wl[c + 3][kr] = f2bf(vv.w);
    }
    __syncthreads();

#pragma unroll
    for (int ks = 0; ks < 2; ++ks) {
      short8 a[2], b[4];
#pragma unroll
      for (int rt = 0; rt < 2; ++rt)
        a[rt] = *reinterpret_cast<const short8*>(&xl[32 * w + 16 * rt + lr][ks * 32 + lg * 8]);
#pragma unroll
      for (int ct = 0; ct < 4; ++ct)
        b[ct] = *reinterpret_cast<const short8*>(&wl[16 * ct + lr][ks * 32 + lg * 8]);
#pragma unroll
      for (int rt = 0; rt < 2; ++rt)
#pragma unroll
        for (int ct = 0; ct < 4; ++ct)
          acc[rt][ct] = __builtin_amdgcn_mfma_f32_16x16x32_bf16(a[rt], b[ct], acc[rt][ct], 0, 0, 0);
    }
  }

  if (blockIdx.y == 2) {
    // vT[b][d][t]: pack 4 consecutive t (the j index) per store
    const int bb = rowbase >> 12;
#pragma unroll
    for (int rt = 0; rt < 2; ++rt) {
      int tloc = (rowbase & 4095) + 32 * w + 16 * rt + 4 * lg;
#pragma unroll
      for (int ct = 0; ct < 4; ++ct) {
        short4v vv;
        vv.x = f2bf(acc[rt][ct][0]); vv.y = f2bf(acc[rt][ct][1]);
        vv.z = f2bf(acc[rt][ct][2]); vv.w = f2bf(acc[rt][ct][3]);
        *reinterpret_cast<short4v*>(&out[((size_t)(bb * 64 + 16 * ct + lr)) * 4096 + tloc]) = vv;
      }
    }
  } else {
    const float sc = (blockIdx.y == 1) ? 0.125f * LOG2E : 1.0f;
#pragma unroll
    for (int rt = 0; rt < 2; ++rt)
#pragma unroll
      for (int ct = 0; ct < 4; ++ct)
#pragma unroll
        for (int j = 0; j < 4; ++j) {
          int grow = rowbase + 32 * w + 16 * rt + lg * 4 + j;
          out[(size_t)grow * 64 + 16 * ct + lr] = f2bf(acc[rt][ct][j] * sc);
        }
  }
}

// KV-split flash attention, LDS-staged double-buffered K/V^T with XOR swizzle.
// Swapped QK^T / PV; lane-local softmax in exp2 domain; one barrier per tile.
__global__ __launch_bounds__(256, 3) void attn_split_kernel(
    const short* __restrict__ qm, const short* __restrict__ km, const short* __restrict__ vT,
    float* __restrict__ opart, float* __restrict__ mpart, float* __restrict__ lpart,
    int S, int chunkTiles)
{
  // bijective XCD-chunked remap (grid = 256*S, always % 8 == 0)
  const int cpx = (256 * S) >> 3;
  int bid = (int)blockIdx.x;
  bid = (bid & 7) * cpx + (bid >> 3);
  const int qidx  = bid / S;
  const int split = bid % S;
  const int b  = qidx >> 6;
  const int qt = qidx & 63;
  const int tid  = threadIdx.x;
  const int w    = tid >> 6;
  const int lane = tid & 63;
  const int lr   = lane & 15;
  const int lg   = lane >> 4;

  __shared__ __align__(16) short kl[2][4096];   // K tile [64][64], swizzled
  __shared__ __align__(16) short vl[2][4096];   // V^T tile [64][64], swizzled
  __shared__ unsigned pl[4][16][36];            // per-wave P transpose buffer

  const short* qb = qm + ((size_t)(b * 4096 + qt * 64 + 16 * w)) * 64;
  const short* kb = km + (size_t)b * 262144;
  const short* vb = vT + (size_t)b * 262144;

  // staging geometry: 512 16B-chunks per tile; thread owns chunks tid and tid+256
  const int r0  = tid >> 3;             // row 0..31
  const int cs0 = (tid & 7) * 8;        // linear col (shorts)
  const int ps0 = r0 * 64 + (cs0 ^ ((r0 & 7) << 3));   // swizzled LDS pos (shorts)
  const int swr = (lr & 7) << 3;        // read-side swizzle (shorts)

  short8 qf[2];
#pragma unroll
  for (int ks = 0; ks < 2; ++ks)
    qf[ks] = *reinterpret_cast<const short8*>(&qb[lr * 64 + ks * 32 + lg * 8]);

  float m = -3e38f, l = 0.f;
  f32x4 o[4];
#pragma unroll
  for (int dt = 0; dt < 4; ++dt) o[dt] = (f32x4){0.f, 0.f, 0.f, 0.f};

  const int kt0 = split * chunkTiles;

  // prologue: stage tile kt0 into buffer 0
  {
    const short* ktb = kb + kt0 * 4096;
    short8 ka  = *reinterpret_cast<const short8*>(ktb + tid * 8);
    short8 kb8 = *reinterpret_cast<const short8*>(ktb + tid * 8 + 2048);
    short8 va  = *reinterpret_cast<const short8*>(&vb[(size_t)r0 * 4096 + kt0 * 64 + cs0]);
    short8 vb8 = *reinterpret_cast<const short8*>(&vb[(size_t)(r0 + 32) * 4096 + kt0 * 64 + cs0]);
    *reinterpret_cast<short8*>(&kl[0][ps0])        = ka;
    *reinterpret_cast<short8*>(&kl[0][ps0 + 2048]) = kb8;
    *reinterpret_cast<short8*>(&vl[0][ps0])        = va;
    *reinterpret_cast<short8*>(&vl[0][ps0 + 2048]) = vb8;
  }
  __syncthreads();

  for (int it = 0; it < chunkTiles; ++it) {
    const int cur = it & 1;
    const short* klc = kl[cur];
    const short* vlc = vl[cur];
    const bool more = (it + 1) < chunkTiles;

    // T14: issue next tile's global loads early; write to LDS late
    short8 ka, kb8, va, vb8;
    if (more) {
      const int kt = kt0 + it + 1;
      const short* ktb = kb + kt * 4096;
      ka  = *reinterpret_cast<const short8*>(ktb + tid * 8);
      kb8 = *reinterpret_cast<const short8*>(ktb + tid * 8 + 2048);
      va  = *reinterpret_cast<const short8*>(&vb[(size_t)r0 * 4096 + kt * 64 + cs0]);
      vb8 = *reinterpret_cast<const short8*>(&vb[(size_t)(r0 + 32) * 4096 + kt * 64 + cs0]);
    }

    // S^T = K Q^T : lane holds s[kt16][j] = S[q=lr][key=16*kt16+4*lg+j]
    f32x4 s[4];
#pragma unroll
    for (int kt16 = 0; kt16 < 4; ++kt16) s[kt16] = (f32x4){0.f, 0.f, 0.f, 0.f};
#pragma unroll
    for (int ks = 0; ks < 2; ++ks)
#pragma unroll
      for (int kt16 = 0; kt16 < 4; ++kt16) {
        short8 kf = *reinterpret_cast<const short8*>(
            &klc[(kt16 * 16 + lr) * 64 + ((ks * 32 + lg * 8) ^ swr)]);
        s[kt16] = __builtin_amdgcn_mfma_f32_16x16x32_bf16(kf, qf[ks], s[kt16], 0, 0, 0);
      }

    // lane-local softmax (exp2 domain; scale*log2e folded into q)
    float pmax = s[0][0];
#pragma unroll
    for (int kt16 = 0; kt16 < 4; ++kt16)
#pragma unroll
      for (int jj = 0; jj < 4; ++jj) pmax = fmaxf(pmax, s[kt16][jj]);
    pmax = fmaxf(pmax, __shfl_xor(pmax, 16));
    pmax = fmaxf(pmax, __shfl_xor(pmax, 32));

    if (__any(pmax > m + 11.5f)) {          // T13 defer-max (8 nats ~ 11.5 bits)
      float mn    = fmaxf(m, pmax);
      float alpha = exp2f(m - mn);
      l *= alpha;
#pragma unroll
      for (int dt = 0; dt < 4; ++dt) o[dt] *= alpha;
      m = mn;
    }

#pragma unroll
    for (int kt16 = 0; kt16 < 4; ++kt16)
#pragma unroll
      for (int jj = 0; jj < 4; ++jj) s[kt16][jj] = exp2f(s[kt16][jj] - m);
    float ps = 0.f;
#pragma unroll
    for (int kt16 = 0; kt16 < 4; ++kt16)
      ps += (s[kt16][0] + s[kt16][1]) + (s[kt16][2] + s[kt16][3]);
    l += ps;

    // pack P into wave-private transpose buffer (compiler inserts lgkm waits)
#pragma unroll
    for (int kt16 = 0; kt16 < 4; ++kt16) {
      pl[w][lr][8 * kt16 + 2 * lg + 0] = pack_bf2(s[kt16][0], s[kt16][1]);
      pl[w][lr][8 * kt16 + 2 * lg + 1] = pack_bf2(s[kt16][2], s[kt16][3]);
    }

    // O^T += V^T P^T
#pragma unroll
    for (int ks = 0; ks < 2; ++ks) {
      short8 pf = *reinterpret_cast<const short8*>(&pl[w][lr][16 * ks + 4 * lg]);
#pragma unroll
      for (int dt = 0; dt < 4; ++dt) {
        short8 vf = *reinterpret_cast<const short8*>(
            &vlc[(dt * 16 + lr) * 64 + ((ks * 32 + lg * 8) ^ swr)]);
        o[dt] = __builtin_amdgcn_mfma_f32_16x16x32_bf16(vf, pf, o[dt], 0, 0, 0);
      }
    }

    if (more) {
      const int nxt = cur ^ 1;
      *reinterpret_cast<short8*>(&kl[nxt][ps0])        = ka;
      *reinterpret_cast<short8*>(&kl[nxt][ps0 + 2048]) = kb8;
      *reinterpret_cast<short8*>(&vl[nxt][ps0])        = va;
      *reinterpret_cast<short8*>(&vl[nxt][ps0 + 2048]) = vb8;
      __syncthreads();   // also drains vmcnt/lgkm: next tile fully staged
    }
  }

  // epilogue
  l += __shfl_xor(l, 16);
  l += __shfl_xor(l, 32);
  const int rowg = b * 4096 + qt * 64 + 16 * w + lr;
  float* ob = opart + ((size_t)split * 16384 + rowg) * 64;
#pragma unroll
  for (int dt = 0; dt < 4; ++dt)
    *reinterpret_cast<f32x4*>(&ob[16 * dt + 4 * lg]) = o[dt];
  if (lane < 16) {
    mpart[split * 16384 + rowg] = m;   // exp2-domain max
    lpart[split * 16384 + rowg] = l;
  }
}

__global__ __launch_bounds__(256) void merge_kernel(
    const float* __restrict__ opart, const float* __restrict__ mpart,
    const float* __restrict__ lpart, float* __restrict__ out, int S)
{
  int gid = blockIdx.x * 256 + threadIdx.x;   // over 16384*16 float4s
  int row = gid >> 4;
  int c4  = (gid & 15) << 2;
  float M = -3e38f;
  for (int s = 0; s < S; ++s) M = fmaxf(M, mpart[s * 16384 + row]);
  float denom = 0.f;
  float ax = 0.f, ay = 0.f, az = 0.f, aw = 0.f;
  for (int s = 0; s < S; ++s) {
    float wgt = exp2f(mpart[s * 16384 + row] - M);
    denom += wgt * lpart[s * 16384 + row];
    float4 op = *reinterpret_cast<const float4*>(&opart[((size_t)s * 16384 + row) * 64 + c4]);
    ax += wgt * op.x; ay += wgt * op.y; az += wgt * op.z; aw += wgt * op.w;
  }
  float inv = 1.f / denom;
  float4 r; r.x = ax * inv; r.y = ay * inv; r.z = az * inv; r.w = aw * inv;
  *reinterpret_cast<float4*>(&out[(size_t)row * 64 + c4]) = r;
}

extern "C" void kernel_launch(void* const* d_in, const int* in_sizes, int n_in,
                              void* d_out, int out_size, void* d_ws, size_t ws_size,
                              hipStream_t stream) {
  const float* x  = (const float*)d_in[0];
  const float* Wk = (const float*)d_in[1];
  const float* Wq = (const float*)d_in[2];
  const float* Wv = (const float*)d_in[3];

  const size_t MH = (size_t)16384 * 64;
  short* kmat = (short*)d_ws;
  short* qmat = kmat + MH;
  short* vTm  = qmat + MH;

  dim3 gproj(16384 / PROJ_BM, 3);
  proj_kernel<<<gproj, 256, 0, stream>>>(x, Wk, Wq, Wv, kmat, qmat, vTm);

  const size_t qkv_bytes = 3 * MH * sizeof(short);                 // 6 MB
  const size_t o_bytes   = MH * sizeof(float);                     // 4 MB / split
  const size_t ml_bytes  = 2 * (size_t)16384 * sizeof(float);
  int S = 8;
  while (S > 1 && qkv_bytes + (size_t)S * (o_bytes + ml_bytes) > ws_size) S >>= 1;

  float* opart = (float*)((char*)d_ws + qkv_bytes);
  float* mpart = opart + (size_t)S * MH;
  float* lpart = mpart + (size_t)S * 16384;
  attn_split_kernel<<<256 * S, 256, 0, stream>>>(qmat, kmat, vTm,
                                                 opart, mpart, lpart, S, 64 / S);
  merge_kernel<<<1024, 256, 0, stream>>>(opart, mpart, lpart, (float*)d_out, S);
}